// Round 12
// baseline (27.682 us; speedup 1.0000x reference)
//
#include <hip/hip_runtime.h>
#include <hip/hip_fp16.h>

#define HH 512
#define WW 512
#define RR 4
#define EPSF 1e-8f

// Block: 512 threads, 32x32 output tile, split-half product staging.
// LDS (bytes, total 42,968 -> 3 WG/CU):
//   [0,     27552): pA/pB/pC h4[28][41]  product h-sums (half-buffer), 2 ch-pairs each
//   [27552, 29848): pD half[28][41]      (sxx22)
//   [29848, 42968): ABh h4[40][41]       (A0,A1,A2,b) full
//   [0,     10560): Ahs h4[40][33]       (aliases pA; live after both halves done)
#define SMEM_BYTES 42968
#define PST 41
#define AST 33
#define PL2 (28 * PST * 2)   // half2 stride between ch-pair planes

struct __align__(8) h4v { __half2 lo, hi; };

__device__ __forceinline__ h4v pack4(float4 v) {
    h4v r; r.lo = __floats2half2_rn(v.x, v.y); r.hi = __floats2half2_rn(v.z, v.w);
    return r;
}
__device__ __forceinline__ float4 ld4s(const float* p, int off, bool v) {
    const float4 r = *(const float4*)(p + (v ? off : 0));
    return v ? r : make_float4(0.f, 0.f, 0.f, 0.f);
}

// 12-float horizontal window (3x aligned float4), zero outside image
#define LOADW(Wv, P) { \
    float4 qa = ld4s((P), gj0 - 4, v0); \
    float4 qb = ld4s((P), gj0,     v1); \
    float4 qc = ld4s((P), gj0 + 4, v2); \
    Wv[0]=qa.x; Wv[1]=qa.y; Wv[2]=qa.z;  Wv[3]=qa.w; \
    Wv[4]=qb.x; Wv[5]=qb.y; Wv[6]=qb.z;  Wv[7]=qb.w; \
    Wv[8]=qc.x; Wv[9]=qc.y; Wv[10]=qc.z; Wv[11]=qc.w; }

// horizontal 9-box of 4 cols via sliding sums -> dst[0..3] (f32)
#define HBOXV(dst, EXPR) { \
    float p[12]; \
    _Pragma("unroll") for (int k = 0; k < 12; ++k) p[k] = (EXPR); \
    dst[0] = ((p[0]+p[1])+(p[2]+p[3])) + ((p[4]+p[5])+(p[6]+p[7])) + p[8]; \
    dst[1] = dst[0] - p[0] + p[9]; \
    dst[2] = dst[1] - p[1] + p[10]; \
    dst[3] = dst[2] - p[2] + p[11]; }

// pack pair (ha[c], hb[c]) -> half2 plane PL, slot HI
#define PSTORE(PL, HI) \
    _Pragma("unroll") for (int c = 0; c < 4; ++c) \
        h2p[(PL) * PL2 + cb2 + (c << 1) + (HI)] = __floats2half2_rn(ha[c], hb[c]);

// 3x3 symmetric solve from grouped box sums -> (A0,A1,A2,b)
__device__ __forceinline__ float4 solve_px(float4 sA, float4 sB, float4 sC, float sD,
                                           float invn) {
    float mx0 = sA.x*invn, mx1 = sA.y*invn, mx2 = sA.z*invn, my = sA.w*invn;
    float cy0 = sB.x*invn - my*mx0;
    float cy1 = sB.y*invn - my*mx1;
    float cy2 = sB.z*invn - my*mx2;
    float a00 = sB.w*invn - mx0*mx0 + EPSF;
    float a01 = sC.x*invn - mx0*mx1;
    float a02 = sC.y*invn - mx0*mx2;
    float a11 = sC.z*invn - mx1*mx1 + EPSF;
    float a12 = sC.w*invn - mx1*mx2;
    float a22 = sD  *invn - mx2*mx2 + EPSF;
    float c00 = a11*a22 - a12*a12;
    float c01 = a02*a12 - a01*a22;
    float c02 = a01*a12 - a02*a11;
    float det = a00*c00 + a01*c01 + a02*c02;
    float id  = 1.0f / det;
    float i00 = c00*id, i01 = c01*id, i02 = c02*id;
    float i11 = (a00*a22 - a02*a02)*id;
    float i12 = (a01*a02 - a00*a12)*id;
    float i22 = (a00*a11 - a01*a01)*id;
    float A0 = cy0*i00 + cy1*i01 + cy2*i02;
    float A1 = cy0*i01 + cy1*i11 + cy2*i12;
    float A2 = cy0*i02 + cy1*i12 + cy2*i22;
    float bb = my - (A0*mx0 + A1*mx1 + A2*mx2);
    return make_float4(A0, A1, A2, bb);
}

// ---- stage 1 (one half): product h-sums for 28 rows x 40 h-cols ----
#define STAGE1(ROFF) \
    if (tid < 280) { \
        const int r   = tid / 10; \
        const int q   = tid % 10; \
        const int gr  = ti - 8 + (ROFF) + r; \
        const int gj0 = tj - 4 + (q << 2); \
        const int hc  = q << 2; \
        const int cb2 = (r * PST + hc) * 2; \
        if (gr >= 0 && gr < HH) { \
            const bool v0 = (unsigned)(gj0 - 4) <= (unsigned)(WW - 4); \
            const bool v1 = (unsigned)(gj0)     <= (unsigned)(WW - 4); \
            const bool v2 = (unsigned)(gj0 + 4) <= (unsigned)(WW - 4); \
            const float* yr = yp + (size_t)gr * WW; \
            const float* ar = xp + (size_t)gr * WW; \
            const float* br = ar + plane; \
            const float* cr = br + plane; \
            float aw[12], bw[12], cw[12], yw[12]; \
            LOADW(aw, ar) LOADW(bw, br) LOADW(cw, cr) LOADW(yw, yr) \
            float ha[4], hb[4]; \
            HBOXV(ha, aw[k])            HBOXV(hb, bw[k]) \
            PSTORE(0, 0) \
            HBOXV(ha, cw[k])            HBOXV(hb, yw[k]) \
            PSTORE(0, 1) \
            HBOXV(ha, yw[k] * aw[k])    HBOXV(hb, yw[k] * bw[k]) \
            PSTORE(1, 0) \
            HBOXV(ha, yw[k] * cw[k])    HBOXV(hb, aw[k] * aw[k]) \
            PSTORE(1, 1) \
            HBOXV(ha, aw[k] * bw[k])    HBOXV(hb, aw[k] * cw[k]) \
            PSTORE(2, 0) \
            HBOXV(ha, bw[k] * bw[k])    HBOXV(hb, bw[k] * cw[k]) \
            PSTORE(2, 1) \
            HBOXV(ha, cw[k] * cw[k]) \
            _Pragma("unroll") for (int c = 0; c < 4; ++c) \
                pD[r * PST + hc + c] = __float2half(ha[c]); \
        } else { \
            const __half2 z2 = __floats2half2_rn(0.f, 0.f); \
            _Pragma("unroll") for (int c = 0; c < 4; ++c) { \
                _Pragma("unroll") for (int pl = 0; pl < 3; ++pl) { \
                    h2p[pl * PL2 + cb2 + (c << 1)]     = z2; \
                    h2p[pl * PL2 + cb2 + (c << 1) + 1] = z2; \
                } \
                pD[r * PST + hc + c] = __float2half(0.f); \
            } \
        } \
    }

#define SOLVH(ABOFF, RL, S) { \
    const int j = (ABOFF) + (RL) + (S); \
    const int I = ti - 4 + j; \
    const bool rv = (unsigned)I < (unsigned)HH; \
    const int i0r = I - RR < 0 ? 0 : I - RR; \
    const int i1r = I + RR > HH - 1 ? HH - 1 : I + RR; \
    const float invn = 1.0f / ((float)(i1r - i0r + 1) * wcnt); \
    float2 xa0 = __half22float2(a0), xa1 = __half22float2(a1); \
    float2 xb0 = __half22float2(b0), xb1 = __half22float2(b1); \
    float2 xc0 = __half22float2(c0), xc1 = __half22float2(c1); \
    float  xd  = __half2float(dd); \
    float4 res = solve_px(make_float4(xa0.x, xa0.y, xa1.x, xa1.y), \
                          make_float4(xb0.x, xb0.y, xb1.x, xb1.y), \
                          make_float4(xc0.x, xc0.y, xc1.x, xc1.y), xd, invn); \
    ABh[j * PST + c] = pack4((cv && rv) ? res : z4); }

#define SLID(RO, RN) { \
    const int o1 = (RO) * PST + c, o2 = (RN) * PST + c; \
    a0 = __hadd2(__hsub2(a0, pA[o1].lo), pA[o2].lo); \
    a1 = __hadd2(__hsub2(a1, pA[o1].hi), pA[o2].hi); \
    b0 = __hadd2(__hsub2(b0, pB[o1].lo), pB[o2].lo); \
    b1 = __hadd2(__hsub2(b1, pB[o1].hi), pB[o2].hi); \
    c0 = __hadd2(__hsub2(c0, pC[o1].lo), pC[o2].lo); \
    c1 = __hadd2(__hsub2(c1, pC[o1].hi), pC[o2].hi); \
    dd = __hadd(__hsub(dd, pD[o1]), pD[o2]); }

// ---- stage 2a (one half): packed vertical 9-sum (sliding quad) + solve, 20 AB rows ----
#define STAGE2A(ABOFF) \
    if (tid < 200) { \
        const int c  = tid % 40; \
        const int rp = tid / 40; \
        const int rl = rp << 2; \
        __half2 a0, a1, b0, b1, c0, c1; \
        __half  dd; \
        { const int o = rl * PST + c; \
          a0 = pA[o].lo; a1 = pA[o].hi; b0 = pB[o].lo; b1 = pB[o].hi; \
          c0 = pC[o].lo; c1 = pC[o].hi; dd = pD[o]; } \
        _Pragma("unroll") for (int k = 1; k < 9; ++k) { \
            const int o = (rl + k) * PST + c; \
            a0 = __hadd2(a0, pA[o].lo); a1 = __hadd2(a1, pA[o].hi); \
            b0 = __hadd2(b0, pB[o].lo); b1 = __hadd2(b1, pB[o].hi); \
            c0 = __hadd2(c0, pC[o].lo); c1 = __hadd2(c1, pC[o].hi); \
            dd = __hadd(dd, pD[o]); } \
        const int gj = tj - 4 + c; \
        const bool cv = (unsigned)gj < (unsigned)WW; \
        const int j0r = gj - RR < 0 ? 0 : gj - RR; \
        const int j1r = gj + RR > WW - 1 ? WW - 1 : gj + RR; \
        const float wcnt = (float)(j1r - j0r + 1); \
        const float4 z4 = make_float4(0.f, 0.f, 0.f, 0.f); \
        __builtin_amdgcn_s_setprio(1); \
        SOLVH(ABOFF, rl, 0) \
        SLID(rl + 0, rl + 9) \
        SOLVH(ABOFF, rl, 1) \
        SLID(rl + 1, rl + 10) \
        SOLVH(ABOFF, rl, 2) \
        SLID(rl + 2, rl + 11) \
        SOLVH(ABOFF, rl, 3) \
        __builtin_amdgcn_s_setprio(0); \
    }

// ==================== fully-fused kernel: y,x -> out ====================
__global__ __launch_bounds__(512, 6) void k_all(const float* __restrict__ y,
                                                const float* __restrict__ x,
                                                float* __restrict__ out) {
    __shared__ __align__(16) char smem[SMEM_BYTES];
    __half2* h2p = (__half2*)smem;              // ch-pair planes, [3][28][41][2]
    h4v*    pA  = (h4v*)smem;                   // [28][41] (pairs 0,1)
    h4v*    pB  = pA + 28 * PST;                // (pairs 2,3)
    h4v*    pC  = pB + 28 * PST;                // (pairs 4,5)
    __half* pD  = (__half*)(smem + 27552);      // [28][41]
    h4v*    ABh = (h4v*)(smem + 29848);         // [40][41]
    h4v*    Ahs = (h4v*)smem;                   // [40][33] (aliases pA)

    const int bid = (int)blockIdx.x;            // 1024
    const int w   = ((bid & 7) << 7) | (bid >> 3);   // XCD slab swizzle
    const int rem = w & 255;
    const int ti  = (rem & 15) << 5;            // row tile
    const int tj  = (rem >> 4) << 5;            // col tile
    const int n   = w >> 8;
    const int tid = (int)threadIdx.x;

    const size_t plane = (size_t)HH * WW;
    const float* yp = y + (size_t)n * plane;
    const float* xp = x + (size_t)(3 * n) * plane;

    // half 1: products rows ti-8..ti+19 -> AB rows 0..19
    STAGE1(0)
    __syncthreads();
    STAGE2A(0)
    __syncthreads();
    // half 2: products rows ti+12..ti+39 (8 rows recomputed) -> AB rows 20..39
    STAGE1(20)
    __syncthreads();
    STAGE2A(20)
    __syncthreads();

    // ---- stage 2b: packed horizontal 9-SUM of ABh -> Ahs[40][33] ----
    if (tid < 320) {
        const int rab = tid >> 3;               // 0..39
        const int q   = tid & 7;                // 0..7
        const int lc  = q << 2;
        h4v wv[12];
#pragma unroll
        for (int k = 0; k < 12; ++k) wv[k] = ABh[rab * PST + lc + k];
        __half2 lo = wv[0].lo, hi = wv[0].hi;
#pragma unroll
        for (int k = 1; k < 9; ++k) { lo = __hadd2(lo, wv[k].lo); hi = __hadd2(hi, wv[k].hi); }
        h4v t; t.lo = lo; t.hi = hi;
        Ahs[rab * AST + lc + 0] = t;
#pragma unroll
        for (int s = 0; s < 3; ++s) {
            lo = __hadd2(__hsub2(lo, wv[s].lo), wv[s + 9].lo);
            hi = __hadd2(__hsub2(hi, wv[s].hi), wv[s + 9].hi);
            t.lo = lo; t.hi = hi;
            Ahs[rab * AST + lc + 1 + s] = t;
        }
    }
    __syncthreads();

    // ---- stage 3: packed vertical 9-sum of Ahs + /N + combine (f32) ----
    {
        const int c3 = tid & 31;
        const int r0 = (tid >> 5) << 1;         // out rows r0, r0+1 (0..31)

        const h4v f0 = Ahs[r0 * AST + c3];
        __half2 slo = f0.lo, shi = f0.hi;
#pragma unroll
        for (int k = 1; k < 9; ++k) {
            const h4v v = Ahs[(r0 + k) * AST + c3];
            slo = __hadd2(slo, v.lo); shi = __hadd2(shi, v.hi);
        }

        const int gj  = tj + c3;
        const int j0r = gj - RR < 0 ? 0 : gj - RR;
        const int j1r = gj + RR > WW - 1 ? WW - 1 : gj + RR;
        const float jcnt = (float)(j1r - j0r + 1);

        float* op = out + (size_t)n * plane;

#define FIN(I) { \
        const int i0r = (I) - RR < 0 ? 0 : (I) - RR; \
        const int i1r = (I) + RR > HH - 1 ? HH - 1 : (I) + RR; \
        const float invn = 1.0f / ((float)(i1r - i0r + 1) * jcnt); \
        float2 flo = __half22float2(slo), fhi = __half22float2(shi); \
        const size_t px = (size_t)(I) * WW + gj; \
        const float x0 = xp[px]; \
        const float x1 = xp[px + plane]; \
        const float x2 = xp[px + 2 * plane]; \
        op[px] = (flo.x * x0 + flo.y * x1 + fhi.x * x2 + fhi.y) * invn; }

        FIN(ti + r0);
        {
            const h4v v9 = Ahs[(r0 + 9) * AST + c3];
            slo = __hadd2(__hsub2(slo, f0.lo), v9.lo);
            shi = __hadd2(__hsub2(shi, f0.hi), v9.hi);
        }
        FIN(ti + r0 + 1);
#undef FIN
    }
}

extern "C" void kernel_launch(void* const* d_in, const int* in_sizes, int n_in,
                              void* d_out, int out_size, void* d_ws, size_t ws_size,
                              hipStream_t stream) {
    const float* y = (const float*)d_in[0];   // (4,1,512,512)
    const float* x = (const float*)d_in[1];   // (4,3,512,512)
    float* out = (float*)d_out;               // (4,1,512,512)

    k_all<<<dim3(1024), dim3(512), 0, stream>>>(y, x, out);
}

// Round 13
// 27.201 us; speedup vs baseline: 1.0177x; 1.0177x over previous
//
#include <hip/hip_runtime.h>
#include <hip/hip_fp16.h>

#define HH 512
#define WW 512
#define RR 4
#define EPSF 1e-8f

// Block: 512 threads, 16x32 output tile, single-pass pipeline (3 barriers).
// LDS (bytes, total 41,984 -> 3 WG/CU = 6 waves/SIMD):
//   [0,     31488): pA/pB/pC h4[32][41]  product h-sums (2 ch-pairs each)
//   [31488, 34112): pD half[32][41]      (sxx22)
//   [34112, 41984): ABh h4[24][41]       (A0,A1,A2,b)
//   [0,      6336): Ahs h4[24][33]       (aliases pA; live after stage 2b)
#define SMEM_BYTES 41984
#define PST 41
#define AST 33
#define PROWS 32
#define PL2 (PROWS * PST * 2)   // half2 stride between ch-pair planes

struct __align__(8) h4v { __half2 lo, hi; };

__device__ __forceinline__ h4v pack4(float4 v) {
    h4v r; r.lo = __floats2half2_rn(v.x, v.y); r.hi = __floats2half2_rn(v.z, v.w);
    return r;
}
__device__ __forceinline__ float4 ld4s(const float* p, int off, bool v) {
    const float4 r = *(const float4*)(p + (v ? off : 0));
    return v ? r : make_float4(0.f, 0.f, 0.f, 0.f);
}

// 12-float horizontal window (3x aligned float4), zero outside image
#define LOADW(Wv, P) { \
    float4 qa = ld4s((P), gj0 - 4, v0); \
    float4 qb = ld4s((P), gj0,     v1); \
    float4 qc = ld4s((P), gj0 + 4, v2); \
    Wv[0]=qa.x; Wv[1]=qa.y; Wv[2]=qa.z;  Wv[3]=qa.w; \
    Wv[4]=qb.x; Wv[5]=qb.y; Wv[6]=qb.z;  Wv[7]=qb.w; \
    Wv[8]=qc.x; Wv[9]=qc.y; Wv[10]=qc.z; Wv[11]=qc.w; }

// horizontal 9-box of 4 cols via sliding sums -> dst[0..3] (f32)
#define HBOXV(dst, EXPR) { \
    float p[12]; \
    _Pragma("unroll") for (int k = 0; k < 12; ++k) p[k] = (EXPR); \
    dst[0] = ((p[0]+p[1])+(p[2]+p[3])) + ((p[4]+p[5])+(p[6]+p[7])) + p[8]; \
    dst[1] = dst[0] - p[0] + p[9]; \
    dst[2] = dst[1] - p[1] + p[10]; \
    dst[3] = dst[2] - p[2] + p[11]; }

// pack pair (ha[c], hb[c]) -> half2 plane PL, slot HI
#define PSTORE(PL, HI) \
    _Pragma("unroll") for (int c = 0; c < 4; ++c) \
        h2p[(PL) * PL2 + cb2 + (c << 1) + (HI)] = __floats2half2_rn(ha[c], hb[c]);

// 3x3 symmetric solve from grouped box sums -> (A0,A1,A2,b)
__device__ __forceinline__ float4 solve_px(float4 sA, float4 sB, float4 sC, float sD,
                                           float invn) {
    float mx0 = sA.x*invn, mx1 = sA.y*invn, mx2 = sA.z*invn, my = sA.w*invn;
    float cy0 = sB.x*invn - my*mx0;
    float cy1 = sB.y*invn - my*mx1;
    float cy2 = sB.z*invn - my*mx2;
    float a00 = sB.w*invn - mx0*mx0 + EPSF;
    float a01 = sC.x*invn - mx0*mx1;
    float a02 = sC.y*invn - mx0*mx2;
    float a11 = sC.z*invn - mx1*mx1 + EPSF;
    float a12 = sC.w*invn - mx1*mx2;
    float a22 = sD  *invn - mx2*mx2 + EPSF;
    float c00 = a11*a22 - a12*a12;
    float c01 = a02*a12 - a01*a22;
    float c02 = a01*a12 - a02*a11;
    float det = a00*c00 + a01*c01 + a02*c02;
    float id  = 1.0f / det;
    float i00 = c00*id, i01 = c01*id, i02 = c02*id;
    float i11 = (a00*a22 - a02*a02)*id;
    float i12 = (a01*a02 - a00*a12)*id;
    float i22 = (a00*a11 - a01*a01)*id;
    float A0 = cy0*i00 + cy1*i01 + cy2*i02;
    float A1 = cy0*i01 + cy1*i11 + cy2*i12;
    float A2 = cy0*i02 + cy1*i12 + cy2*i22;
    float bb = my - (A0*mx0 + A1*mx1 + A2*mx2);
    return make_float4(A0, A1, A2, bb);
}

// ==================== fully-fused kernel: y,x -> out ====================
__global__ __launch_bounds__(512, 6) void k_all(const float* __restrict__ y,
                                                const float* __restrict__ x,
                                                float* __restrict__ out) {
    __shared__ __align__(16) char smem[SMEM_BYTES];
    __half2* h2p = (__half2*)smem;              // ch-pair planes [3][32][41][2]
    h4v*    pA  = (h4v*)smem;                   // [32][41] (pairs 0,1)
    h4v*    pB  = pA + PROWS * PST;             // (pairs 2,3)
    h4v*    pC  = pB + PROWS * PST;             // (pairs 4,5)
    __half* pD  = (__half*)(smem + 31488);      // [32][41]
    h4v*    ABh = (h4v*)(smem + 34112);         // [24][41]
    h4v*    Ahs = (h4v*)smem;                   // [24][33] (aliases pA)

    const int bid = (int)blockIdx.x;            // 2048
    const int w   = ((bid & 7) << 8) | (bid >> 3);   // XCD slab swizzle
    const int rem = w & 511;
    const int ti  = (rem & 31) << 4;            // row tile (16 rows)
    const int tj  = (rem >> 5) << 5;            // col tile (32 cols)
    const int n   = w >> 9;
    const int tid = (int)threadIdx.x;

    const size_t plane = (size_t)HH * WW;
    const float* yp = y + (size_t)n * plane;
    const float* xp = x + (size_t)(3 * n) * plane;

    // ---- stage 1: product h-sums, 32 rows x 40 h-cols (320 tasks) ----
    if (tid < 320) {
        const int r   = tid / 10;               // 0..31 (gr = ti-8+r)
        const int q   = tid % 10;               // 0..9
        const int gr  = ti - 8 + r;
        const int gj0 = tj - 4 + (q << 2);
        const int hc  = q << 2;
        const int cb2 = (r * PST + hc) * 2;
        if (gr >= 0 && gr < HH) {
            const bool v0 = (unsigned)(gj0 - 4) <= (unsigned)(WW - 4);
            const bool v1 = (unsigned)(gj0)     <= (unsigned)(WW - 4);
            const bool v2 = (unsigned)(gj0 + 4) <= (unsigned)(WW - 4);
            const float* yr = yp + (size_t)gr * WW;
            const float* ar = xp + (size_t)gr * WW;
            const float* br = ar + plane;
            const float* cr = br + plane;
            float aw[12], bw[12], cw[12], yw[12];
            LOADW(aw, ar) LOADW(bw, br) LOADW(cw, cr) LOADW(yw, yr)
            float ha[4], hb[4];
            HBOXV(ha, aw[k])            HBOXV(hb, bw[k])
            PSTORE(0, 0)
            HBOXV(ha, cw[k])            HBOXV(hb, yw[k])
            PSTORE(0, 1)
            HBOXV(ha, yw[k] * aw[k])    HBOXV(hb, yw[k] * bw[k])
            PSTORE(1, 0)
            HBOXV(ha, yw[k] * cw[k])    HBOXV(hb, aw[k] * aw[k])
            PSTORE(1, 1)
            HBOXV(ha, aw[k] * bw[k])    HBOXV(hb, aw[k] * cw[k])
            PSTORE(2, 0)
            HBOXV(ha, bw[k] * bw[k])    HBOXV(hb, bw[k] * cw[k])
            PSTORE(2, 1)
            HBOXV(ha, cw[k] * cw[k])
#pragma unroll
            for (int c = 0; c < 4; ++c)
                pD[r * PST + hc + c] = __float2half(ha[c]);
        } else {
            const __half2 z2 = __floats2half2_rn(0.f, 0.f);
#pragma unroll
            for (int c = 0; c < 4; ++c) {
#pragma unroll
                for (int pl = 0; pl < 3; ++pl) {
                    h2p[pl * PL2 + cb2 + (c << 1)]     = z2;
                    h2p[pl * PL2 + cb2 + (c << 1) + 1] = z2;
                }
                pD[r * PST + hc + c] = __float2half(0.f);
            }
        }
    }
    __syncthreads();

    // ---- stage 2a: packed vertical 9-sum (sliding quad) + f32 solve -> ABh[24][41] ----
    if (tid < 240) {
        const int c   = tid % 40;
        const int rp  = tid / 40;               // 0..5
        const int rab = rp << 2;                // AB rows rab..rab+3; window rows rab..rab+11

        __half2 a0, a1, b0, b1, c0, c1;
        __half  dd;
        {
            const int o = rab * PST + c;
            a0 = pA[o].lo; a1 = pA[o].hi;
            b0 = pB[o].lo; b1 = pB[o].hi;
            c0 = pC[o].lo; c1 = pC[o].hi;
            dd = pD[o];
        }
#pragma unroll
        for (int k = 1; k < 9; ++k) {
            const int o = (rab + k) * PST + c;
            a0 = __hadd2(a0, pA[o].lo); a1 = __hadd2(a1, pA[o].hi);
            b0 = __hadd2(b0, pB[o].lo); b1 = __hadd2(b1, pB[o].hi);
            c0 = __hadd2(c0, pC[o].lo); c1 = __hadd2(c1, pC[o].hi);
            dd = __hadd(dd, pD[o]);
        }

        const int gj = tj - 4 + c;
        const bool cv = (unsigned)gj < (unsigned)WW;
        const int j0r = gj - RR < 0 ? 0 : gj - RR;
        const int j1r = gj + RR > WW - 1 ? WW - 1 : gj + RR;
        const float wcnt = (float)(j1r - j0r + 1);
        const float4 z4 = make_float4(0.f, 0.f, 0.f, 0.f);

#define SOLVH(RO) { \
        const int I = ti - 4 + (RO); \
        const bool rv = (unsigned)I < (unsigned)HH; \
        const int i0r = I - RR < 0 ? 0 : I - RR; \
        const int i1r = I + RR > HH - 1 ? HH - 1 : I + RR; \
        const float invn = 1.0f / ((float)(i1r - i0r + 1) * wcnt); \
        float2 xa0 = __half22float2(a0), xa1 = __half22float2(a1); \
        float2 xb0 = __half22float2(b0), xb1 = __half22float2(b1); \
        float2 xc0 = __half22float2(c0), xc1 = __half22float2(c1); \
        float  xd  = __half2float(dd); \
        float4 res = solve_px(make_float4(xa0.x, xa0.y, xa1.x, xa1.y), \
                              make_float4(xb0.x, xb0.y, xb1.x, xb1.y), \
                              make_float4(xc0.x, xc0.y, xc1.x, xc1.y), xd, invn); \
        ABh[(RO) * PST + c] = pack4((cv && rv) ? res : z4); }

#define SLID(RO, RN) { \
        const int o1 = (RO) * PST + c, o2 = (RN) * PST + c; \
        a0 = __hadd2(__hsub2(a0, pA[o1].lo), pA[o2].lo); \
        a1 = __hadd2(__hsub2(a1, pA[o1].hi), pA[o2].hi); \
        b0 = __hadd2(__hsub2(b0, pB[o1].lo), pB[o2].lo); \
        b1 = __hadd2(__hsub2(b1, pB[o1].hi), pB[o2].hi); \
        c0 = __hadd2(__hsub2(c0, pC[o1].lo), pC[o2].lo); \
        c1 = __hadd2(__hsub2(c1, pC[o1].hi), pC[o2].hi); \
        dd = __hadd(__hsub(dd, pD[o1]), pD[o2]); }

        __builtin_amdgcn_s_setprio(1);
        SOLVH(rab)
        SLID(rab,     rab + 9)
        SOLVH(rab + 1)
        SLID(rab + 1, rab + 10)
        SOLVH(rab + 2)
        SLID(rab + 2, rab + 11)
        SOLVH(rab + 3)
        __builtin_amdgcn_s_setprio(0);
#undef SOLVH
#undef SLID
    }
    __syncthreads();

    // ---- stage 2b: packed horizontal 9-SUM of ABh -> Ahs[24][33] ----
    if (tid < 192) {
        const int rab = tid >> 3;               // 0..23
        const int q   = tid & 7;                // 0..7
        const int lc  = q << 2;
        h4v wv[12];
#pragma unroll
        for (int k = 0; k < 12; ++k) wv[k] = ABh[rab * PST + lc + k];
        __half2 lo = wv[0].lo, hi = wv[0].hi;
#pragma unroll
        for (int k = 1; k < 9; ++k) { lo = __hadd2(lo, wv[k].lo); hi = __hadd2(hi, wv[k].hi); }
        h4v t; t.lo = lo; t.hi = hi;
        Ahs[rab * AST + lc + 0] = t;
#pragma unroll
        for (int s = 0; s < 3; ++s) {
            lo = __hadd2(__hsub2(lo, wv[s].lo), wv[s + 9].lo);
            hi = __hadd2(__hsub2(hi, wv[s].hi), wv[s + 9].hi);
            t.lo = lo; t.hi = hi;
            Ahs[rab * AST + lc + 1 + s] = t;
        }
    }
    __syncthreads();

    // ---- stage 3: packed vertical 9-sum of Ahs + /N + combine (f32) ----
    if (tid < 256) {
        const int c3 = tid & 31;
        const int r0 = (tid >> 5) << 1;         // out rows r0, r0+1 (0..15)

        const h4v f0 = Ahs[r0 * AST + c3];
        __half2 slo = f0.lo, shi = f0.hi;
#pragma unroll
        for (int k = 1; k < 9; ++k) {
            const h4v v = Ahs[(r0 + k) * AST + c3];
            slo = __hadd2(slo, v.lo); shi = __hadd2(shi, v.hi);
        }

        const int gj  = tj + c3;
        const int j0r = gj - RR < 0 ? 0 : gj - RR;
        const int j1r = gj + RR > WW - 1 ? WW - 1 : gj + RR;
        const float jcnt = (float)(j1r - j0r + 1);

        float* op = out + (size_t)n * plane;

#define FIN(I) { \
        const int i0r = (I) - RR < 0 ? 0 : (I) - RR; \
        const int i1r = (I) + RR > HH - 1 ? HH - 1 : (I) + RR; \
        const float invn = 1.0f / ((float)(i1r - i0r + 1) * jcnt); \
        float2 flo = __half22float2(slo), fhi = __half22float2(shi); \
        const size_t px = (size_t)(I) * WW + gj; \
        const float x0 = xp[px]; \
        const float x1 = xp[px + plane]; \
        const float x2 = xp[px + 2 * plane]; \
        op[px] = (flo.x * x0 + flo.y * x1 + fhi.x * x2 + fhi.y) * invn; }

        FIN(ti + r0);
        {
            const h4v v9 = Ahs[(r0 + 9) * AST + c3];
            slo = __hadd2(__hsub2(slo, f0.lo), v9.lo);
            shi = __hadd2(__hsub2(shi, f0.hi), v9.hi);
        }
        FIN(ti + r0 + 1);
#undef FIN
    }
}

extern "C" void kernel_launch(void* const* d_in, const int* in_sizes, int n_in,
                              void* d_out, int out_size, void* d_ws, size_t ws_size,
                              hipStream_t stream) {
    const float* y = (const float*)d_in[0];   // (4,1,512,512)
    const float* x = (const float*)d_in[1];   // (4,3,512,512)
    float* out = (float*)d_out;               // (4,1,512,512)

    k_all<<<dim3(2048), dim3(512), 0, stream>>>(y, x, out);
}

// Round 14
// 26.526 us; speedup vs baseline: 1.0436x; 1.0254x over previous
//
#include <hip/hip_runtime.h>
#include <hip/hip_fp16.h>

#define HH 512
#define WW 512
#define RR 4
#define EPSF 1e-8f

// Block: 512 threads, 32x32 output tile. LDS (bytes, total 64,288 -> 2 WG/CU):
//   [0,     15744): pA  h4[48][41]   (sx0,sx1,sx2,sy)        stages 1-2a
//   [15744, 31488): pB  h4[48][41]   (syx0,syx1,syx2,sxx00)  stages 1-2a
//   [31488, 47232): pC  h4[48][41]   (sxx01,sxx02,sxx11,sxx12)
//   [47232, 51168): pD  half[48][41] (sxx22)                 stages 1-2a
//   [51168, 64288): ABh h4[40][41]   (A0,A1,A2,b)            stages 2a-2b
//   [0,     10560): Ahs h4[40][33]   (aliases pA)            stages 2b-3
#define SMEM_BYTES 64288
#define PST 41
#define AST 33

struct __align__(8) h4v { __half2 lo, hi; };

__device__ __forceinline__ h4v pack4(float4 v) {
    h4v r; r.lo = __floats2half2_rn(v.x, v.y); r.hi = __floats2half2_rn(v.z, v.w);
    return r;
}
__device__ __forceinline__ float4 ld4s(const float* p, int off, bool v) {
    const float4 r = *(const float4*)(p + (v ? off : 0));
    return v ? r : make_float4(0.f, 0.f, 0.f, 0.f);
}

#define HBOX(ch, EXPR) { \
    float p[12]; \
    _Pragma("unroll") for (int k = 0; k < 12; ++k) p[k] = (EXPR); \
    hs[ch][0] = ((p[0]+p[1])+(p[2]+p[3])) + ((p[4]+p[5])+(p[6]+p[7])) + p[8]; \
    hs[ch][1] = hs[ch][0] - p[0] + p[9]; \
    hs[ch][2] = hs[ch][1] - p[1] + p[10]; \
    hs[ch][3] = hs[ch][2] - p[2] + p[11]; }

// 3x3 symmetric solve from grouped box sums -> (A0,A1,A2,b)
__device__ __forceinline__ float4 solve_px(float4 sA, float4 sB, float4 sC, float sD,
                                           float invn) {
    float mx0 = sA.x*invn, mx1 = sA.y*invn, mx2 = sA.z*invn, my = sA.w*invn;
    float cy0 = sB.x*invn - my*mx0;
    float cy1 = sB.y*invn - my*mx1;
    float cy2 = sB.z*invn - my*mx2;
    float a00 = sB.w*invn - mx0*mx0 + EPSF;
    float a01 = sC.x*invn - mx0*mx1;
    float a02 = sC.y*invn - mx0*mx2;
    float a11 = sC.z*invn - mx1*mx1 + EPSF;
    float a12 = sC.w*invn - mx1*mx2;
    float a22 = sD  *invn - mx2*mx2 + EPSF;
    float c00 = a11*a22 - a12*a12;
    float c01 = a02*a12 - a01*a22;
    float c02 = a01*a12 - a02*a11;
    float det = a00*c00 + a01*c01 + a02*c02;
    float id  = 1.0f / det;
    float i00 = c00*id, i01 = c01*id, i02 = c02*id;
    float i11 = (a00*a22 - a02*a02)*id;
    float i12 = (a01*a02 - a00*a12)*id;
    float i22 = (a00*a11 - a01*a01)*id;
    float A0 = cy0*i00 + cy1*i01 + cy2*i02;
    float A1 = cy0*i01 + cy1*i11 + cy2*i12;
    float A2 = cy0*i02 + cy1*i12 + cy2*i22;
    float bb = my - (A0*mx0 + A1*mx1 + A2*mx2);
    return make_float4(A0, A1, A2, bb);
}

// ==================== fully-fused kernel: y,x -> out ====================
__global__ __launch_bounds__(512, 4) void k_all(const float* __restrict__ y,
                                                const float* __restrict__ x,
                                                float* __restrict__ out) {
    __shared__ __align__(16) char smem[SMEM_BYTES];
    h4v*    pA  = (h4v*)smem;                   // [48][41]
    h4v*    pB  = pA + 48 * PST;
    h4v*    pC  = pB + 48 * PST;
    __half* pD  = (__half*)(smem + 47232);      // [48][41]
    h4v*    ABh = (h4v*)(smem + 51168);         // [40][41]
    h4v*    Ahs = (h4v*)smem;                   // [40][33] (aliases pA)

    const int bid = (int)blockIdx.x;            // 1024
    const int w   = ((bid & 7) << 7) | (bid >> 3);   // XCD slab swizzle
    const int rem = w & 255;
    const int ti  = (rem & 15) << 5;            // row tile
    const int tj  = (rem >> 4) << 5;            // col tile
    const int n   = w >> 8;
    const int tid = (int)threadIdx.x;

    const size_t plane = (size_t)HH * WW;
    const float* yp = y + (size_t)n * plane;
    const float* xp = x + (size_t)(3 * n) * plane;

    // ---- prefetch stage-3 x reads (independent of all LDS phases) ----
    const int c3  = tid & 31;
    const int r30 = (tid >> 5) << 1;            // out rows r30, r30+1
    const int gj3 = tj + c3;
    const size_t px0 = (size_t)(ti + r30) * WW + gj3;
    const size_t px1 = px0 + WW;
    const float x00 = xp[px0], x01 = xp[px0 + plane], x02 = xp[px0 + 2 * plane];
    const float x10 = xp[px1], x11 = xp[px1 + plane], x12 = xp[px1 + 2 * plane];

    // ---- stage 1: product h-sums, 48 rows x 40 h-cols (480 tasks, 1/thread) ----
    if (tid < 480) {
        const int r   = tid / 10;               // 0..47 (gr = ti-8+r)
        const int q   = tid % 10;               // 0..9
        const int gr  = ti - 8 + r;
        const int gj0 = tj - 4 + (q << 2);
        const int hc  = q << 2;
        if (gr >= 0 && gr < HH) {
            const bool v0 = (unsigned)(gj0 - 4) <= (unsigned)(WW - 4);
            const bool v1 = (unsigned)(gj0)     <= (unsigned)(WW - 4);
            const bool v2 = (unsigned)(gj0 + 4) <= (unsigned)(WW - 4);
            const float* yr = yp + (size_t)gr * WW;
            const float* ar = xp + (size_t)gr * WW;
            const float* br = ar + plane;
            const float* cr = br + plane;
#define LOADW(Wv, P) { \
            float4 qa = ld4s((P), gj0 - 4, v0); \
            float4 qb = ld4s((P), gj0,     v1); \
            float4 qc = ld4s((P), gj0 + 4, v2); \
            Wv[0]=qa.x; Wv[1]=qa.y; Wv[2]=qa.z;  Wv[3]=qa.w; \
            Wv[4]=qb.x; Wv[5]=qb.y; Wv[6]=qb.z;  Wv[7]=qb.w; \
            Wv[8]=qc.x; Wv[9]=qc.y; Wv[10]=qc.z; Wv[11]=qc.w; }
            float aw[12], bw[12], cw[12], yw[12];
            LOADW(aw, ar); LOADW(bw, br); LOADW(cw, cr); LOADW(yw, yr);
#undef LOADW
            float hs[13][4];
            HBOX(0,  aw[k]);
            HBOX(1,  bw[k]);
            HBOX(2,  cw[k]);
            HBOX(3,  yw[k]);
            HBOX(4,  yw[k] * aw[k]);
            HBOX(5,  yw[k] * bw[k]);
            HBOX(6,  yw[k] * cw[k]);
            HBOX(7,  aw[k] * aw[k]);
            HBOX(8,  aw[k] * bw[k]);
            HBOX(9,  aw[k] * cw[k]);
            HBOX(10, bw[k] * bw[k]);
            HBOX(11, bw[k] * cw[k]);
            HBOX(12, cw[k] * cw[k]);
#pragma unroll
            for (int c = 0; c < 4; ++c) {
                pA[r * PST + hc + c] = pack4(make_float4(hs[0][c], hs[1][c], hs[2][c],  hs[3][c]));
                pB[r * PST + hc + c] = pack4(make_float4(hs[4][c], hs[5][c], hs[6][c],  hs[7][c]));
                pC[r * PST + hc + c] = pack4(make_float4(hs[8][c], hs[9][c], hs[10][c], hs[11][c]));
                pD[r * PST + hc + c] = __float2half(hs[12][c]);
            }
        } else {
            const h4v z = pack4(make_float4(0.f, 0.f, 0.f, 0.f));
#pragma unroll
            for (int c = 0; c < 4; ++c) {
                pA[r * PST + hc + c] = z; pB[r * PST + hc + c] = z;
                pC[r * PST + hc + c] = z; pD[r * PST + hc + c] = __float2half(0.f);
            }
        }
    }
    __syncthreads();

    // ---- stage 2a: packed-fp16 vertical 9-sum (sliding quad) + f32 solve -> ABh ----
    if (tid < 400) {
        const int c   = tid % 40;
        const int rp  = tid / 40;               // 0..9
        const int rab = rp << 2;                // AB rows rab..rab+3

        __half2 a0, a1, b0, b1, c0, c1;
        __half  dd;
        {
            const int o = rab * PST + c;
            a0 = pA[o].lo; a1 = pA[o].hi;
            b0 = pB[o].lo; b1 = pB[o].hi;
            c0 = pC[o].lo; c1 = pC[o].hi;
            dd = pD[o];
        }
#pragma unroll
        for (int k = 1; k < 9; ++k) {
            const int o = (rab + k) * PST + c;
            a0 = __hadd2(a0, pA[o].lo); a1 = __hadd2(a1, pA[o].hi);
            b0 = __hadd2(b0, pB[o].lo); b1 = __hadd2(b1, pB[o].hi);
            c0 = __hadd2(c0, pC[o].lo); c1 = __hadd2(c1, pC[o].hi);
            dd = __hadd(dd, pD[o]);
        }

        const int gj = tj - 4 + c;
        const bool cv = (unsigned)gj < (unsigned)WW;
        const int j0r = gj - RR < 0 ? 0 : gj - RR;
        const int j1r = gj + RR > WW - 1 ? WW - 1 : gj + RR;
        const float wcnt = (float)(j1r - j0r + 1);
        const float4 z4 = make_float4(0.f, 0.f, 0.f, 0.f);

#define SOLVH(RO) { \
        const int I = ti - 4 + (RO); \
        const bool rv = (unsigned)I < (unsigned)HH; \
        const int i0r = I - RR < 0 ? 0 : I - RR; \
        const int i1r = I + RR > HH - 1 ? HH - 1 : I + RR; \
        const float invn = 1.0f / ((float)(i1r - i0r + 1) * wcnt); \
        float2 xa0 = __half22float2(a0), xa1 = __half22float2(a1); \
        float2 xb0 = __half22float2(b0), xb1 = __half22float2(b1); \
        float2 xc0 = __half22float2(c0), xc1 = __half22float2(c1); \
        float  xd  = __half2float(dd); \
        float4 res = solve_px(make_float4(xa0.x, xa0.y, xa1.x, xa1.y), \
                              make_float4(xb0.x, xb0.y, xb1.x, xb1.y), \
                              make_float4(xc0.x, xc0.y, xc1.x, xc1.y), xd, invn); \
        ABh[(RO) * PST + c] = pack4((cv && rv) ? res : z4); }

#define SLID(RO, RN) { \
        const int o1 = (RO) * PST + c, o2 = (RN) * PST + c; \
        a0 = __hadd2(__hsub2(a0, pA[o1].lo), pA[o2].lo); \
        a1 = __hadd2(__hsub2(a1, pA[o1].hi), pA[o2].hi); \
        b0 = __hadd2(__hsub2(b0, pB[o1].lo), pB[o2].lo); \
        b1 = __hadd2(__hsub2(b1, pB[o1].hi), pB[o2].hi); \
        c0 = __hadd2(__hsub2(c0, pC[o1].lo), pC[o2].lo); \
        c1 = __hadd2(__hsub2(c1, pC[o1].hi), pC[o2].hi); \
        dd = __hadd(__hsub(dd, pD[o1]), pD[o2]); }

        __builtin_amdgcn_s_setprio(1);
        SOLVH(rab)
        SLID(rab,     rab + 9)
        SOLVH(rab + 1)
        SLID(rab + 1, rab + 10)
        SOLVH(rab + 2)
        SLID(rab + 2, rab + 11)
        SOLVH(rab + 3)
        __builtin_amdgcn_s_setprio(0);
#undef SOLVH
#undef SLID
    }
    __syncthreads();

    // ---- stage 2b: packed-fp16 horizontal 9-SUM of ABh -> Ahs[40][33] ----
    if (tid < 320) {
        const int rab = tid >> 3;               // 0..39
        const int q   = tid & 7;                // 0..7
        const int lc  = q << 2;
        h4v wv[12];
#pragma unroll
        for (int k = 0; k < 12; ++k) wv[k] = ABh[rab * PST + lc + k];
        __half2 lo = wv[0].lo, hi = wv[0].hi;
#pragma unroll
        for (int k = 1; k < 9; ++k) { lo = __hadd2(lo, wv[k].lo); hi = __hadd2(hi, wv[k].hi); }
        h4v t; t.lo = lo; t.hi = hi;
        Ahs[rab * AST + lc + 0] = t;
#pragma unroll
        for (int s = 0; s < 3; ++s) {
            lo = __hadd2(__hsub2(lo, wv[s].lo), wv[s + 9].lo);
            hi = __hadd2(__hsub2(hi, wv[s].hi), wv[s + 9].hi);
            t.lo = lo; t.hi = hi;
            Ahs[rab * AST + lc + 1 + s] = t;
        }
    }
    __syncthreads();

    // ---- stage 3: packed-fp16 vertical 9-sum of Ahs + /N + combine (f32) ----
    {
        const h4v f0 = Ahs[r30 * AST + c3];
        __half2 slo = f0.lo, shi = f0.hi;
#pragma unroll
        for (int k = 1; k < 9; ++k) {
            const h4v v = Ahs[(r30 + k) * AST + c3];
            slo = __hadd2(slo, v.lo); shi = __hadd2(shi, v.hi);
        }

        const int j0r = gj3 - RR < 0 ? 0 : gj3 - RR;
        const int j1r = gj3 + RR > WW - 1 ? WW - 1 : gj3 + RR;
        const float jcnt = (float)(j1r - j0r + 1);

        float* op = out + (size_t)n * plane;

#define FIN(I, PX, X0, X1, X2) { \
        const int i0r = (I) - RR < 0 ? 0 : (I) - RR; \
        const int i1r = (I) + RR > HH - 1 ? HH - 1 : (I) + RR; \
        const float invn = 1.0f / ((float)(i1r - i0r + 1) * jcnt); \
        float2 flo = __half22float2(slo), fhi = __half22float2(shi); \
        op[PX] = (flo.x * (X0) + flo.y * (X1) + fhi.x * (X2) + fhi.y) * invn; }

        FIN(ti + r30, px0, x00, x01, x02);
        {
            const h4v v9 = Ahs[(r30 + 9) * AST + c3];
            slo = __hadd2(__hsub2(slo, f0.lo), v9.lo);
            shi = __hadd2(__hsub2(shi, f0.hi), v9.hi);
        }
        FIN(ti + r30 + 1, px1, x10, x11, x12);
#undef FIN
    }
}

extern "C" void kernel_launch(void* const* d_in, const int* in_sizes, int n_in,
                              void* d_out, int out_size, void* d_ws, size_t ws_size,
                              hipStream_t stream) {
    const float* y = (const float*)d_in[0];   // (4,1,512,512)
    const float* x = (const float*)d_in[1];   // (4,3,512,512)
    float* out = (float*)d_out;               // (4,1,512,512)

    k_all<<<dim3(1024), dim3(512), 0, stream>>>(y, x, out);
}

// Round 15
// 24.246 us; speedup vs baseline: 1.1417x; 1.0940x over previous
//
#include <hip/hip_runtime.h>
#include <hip/hip_fp16.h>

#define HH 512
#define WW 512
#define NB 4
#define RR 4
#define EPSF 1e-8f

// Block: 512 threads, 32x32 output tile. LDS (bytes, total 64,288 -> 2 WG/CU):
//   [0,     15744): pA  h4[48][41]   (sx0,sx1,sx2,sy)        stages 1-2a
//   [15744, 31488): pB  h4[48][41]   (syx0,syx1,syx2,sxx00)  stages 1-2a
//   [31488, 47232): pC  h4[48][41]   (sxx01,sxx02,sxx11,sxx12)
//   [47232, 51168): pD  half[48][41] (sxx22)                 stages 1-2a
//   [51168, 64288): ABh h4[40][41]   (A0,A1,A2,b)            stages 2a-2b
//   [0,     10560): Ahs h4[40][33]   (aliases pA)            stages 2b-3
// NOTE (R12-R14 post-mortems): this exact structure is a sharp local optimum.
//   - 3 WG/CU via split-half staging: +3.4 us (extra barrier phases serialize loads)
//   - 3 WG/CU via 16x32 tile: +2.9 us (halo redundancy + same sync structure)
//   - x-prefetch + setprio: +2.2 us (VGPR pressure + delayed stage-1 loads)
// Do not perturb without a counter-backed reason.
#define SMEM_BYTES 64288
#define PST 41
#define AST 33

struct __align__(8) h4v { __half2 lo, hi; };

__device__ __forceinline__ h4v pack4(float4 v) {
    h4v r; r.lo = __floats2half2_rn(v.x, v.y); r.hi = __floats2half2_rn(v.z, v.w);
    return r;
}
__device__ __forceinline__ float4 f4add(float4 a, float4 b) {
    return make_float4(a.x + b.x, a.y + b.y, a.z + b.z, a.w + b.w);
}
__device__ __forceinline__ float4 f4sub(float4 a, float4 b) {
    return make_float4(a.x - b.x, a.y - b.y, a.z - b.z, a.w - b.w);
}
__device__ __forceinline__ float4 ld4s(const float* p, int off, bool v) {
    const float4 r = *(const float4*)(p + (v ? off : 0));
    return v ? r : make_float4(0.f, 0.f, 0.f, 0.f);
}

#define HBOX(ch, EXPR) { \
    float p[12]; \
    _Pragma("unroll") for (int k = 0; k < 12; ++k) p[k] = (EXPR); \
    hs[ch][0] = ((p[0]+p[1])+(p[2]+p[3])) + ((p[4]+p[5])+(p[6]+p[7])) + p[8]; \
    hs[ch][1] = hs[ch][0] - p[0] + p[9]; \
    hs[ch][2] = hs[ch][1] - p[1] + p[10]; \
    hs[ch][3] = hs[ch][2] - p[2] + p[11]; }

// 3x3 symmetric solve from grouped box sums -> (A0,A1,A2,b)
__device__ __forceinline__ float4 solve_px(float4 sA, float4 sB, float4 sC, float sD,
                                           float invn) {
    float mx0 = sA.x*invn, mx1 = sA.y*invn, mx2 = sA.z*invn, my = sA.w*invn;
    float cy0 = sB.x*invn - my*mx0;
    float cy1 = sB.y*invn - my*mx1;
    float cy2 = sB.z*invn - my*mx2;
    float a00 = sB.w*invn - mx0*mx0 + EPSF;
    float a01 = sC.x*invn - mx0*mx1;
    float a02 = sC.y*invn - mx0*mx2;
    float a11 = sC.z*invn - mx1*mx1 + EPSF;
    float a12 = sC.w*invn - mx1*mx2;
    float a22 = sD  *invn - mx2*mx2 + EPSF;
    float c00 = a11*a22 - a12*a12;
    float c01 = a02*a12 - a01*a22;
    float c02 = a01*a12 - a02*a11;
    float det = a00*c00 + a01*c01 + a02*c02;
    float id  = 1.0f / det;
    float i00 = c00*id, i01 = c01*id, i02 = c02*id;
    float i11 = (a00*a22 - a02*a02)*id;
    float i12 = (a01*a02 - a00*a12)*id;
    float i22 = (a00*a11 - a01*a01)*id;
    float A0 = cy0*i00 + cy1*i01 + cy2*i02;
    float A1 = cy0*i01 + cy1*i11 + cy2*i12;
    float A2 = cy0*i02 + cy1*i12 + cy2*i22;
    float bb = my - (A0*mx0 + A1*mx1 + A2*mx2);
    return make_float4(A0, A1, A2, bb);
}

// ==================== fully-fused kernel: y,x -> out ====================
__global__ __launch_bounds__(512, 4) void k_all(const float* __restrict__ y,
                                                const float* __restrict__ x,
                                                float* __restrict__ out) {
    __shared__ __align__(16) char smem[SMEM_BYTES];
    h4v*    pA  = (h4v*)smem;                   // [48][41]
    h4v*    pB  = pA + 48 * PST;
    h4v*    pC  = pB + 48 * PST;
    __half* pD  = (__half*)(smem + 47232);      // [48][41]
    h4v*    ABh = (h4v*)(smem + 51168);         // [40][41]
    h4v*    Ahs = (h4v*)smem;                   // [40][33] (aliases pA)

    const int bid = (int)blockIdx.x;            // 1024
    const int w   = ((bid & 7) << 7) | (bid >> 3);   // XCD slab swizzle
    const int rem = w & 255;
    const int ti  = (rem & 15) << 5;            // row tile
    const int tj  = (rem >> 4) << 5;            // col tile
    const int n   = w >> 8;
    const int tid = (int)threadIdx.x;

    const size_t plane = (size_t)HH * WW;
    const float* yp = y + (size_t)n * plane;
    const float* xp = x + (size_t)(3 * n) * plane;

    // ---- stage 1: product h-sums, 48 rows x 40 h-cols (480 tasks, 1/thread) ----
    if (tid < 480) {
        const int r   = tid / 10;               // 0..47 (gr = ti-8+r)
        const int q   = tid % 10;               // 0..9
        const int gr  = ti - 8 + r;
        const int gj0 = tj - 4 + (q << 2);
        const int hc  = q << 2;
        if (gr >= 0 && gr < HH) {
            const bool v0 = (unsigned)(gj0 - 4) <= (unsigned)(WW - 4);
            const bool v1 = (unsigned)(gj0)     <= (unsigned)(WW - 4);
            const bool v2 = (unsigned)(gj0 + 4) <= (unsigned)(WW - 4);
            const float* yr = yp + (size_t)gr * WW;
            const float* ar = xp + (size_t)gr * WW;
            const float* br = ar + plane;
            const float* cr = br + plane;
#define LOADW(Wv, P) { \
            float4 qa = ld4s((P), gj0 - 4, v0); \
            float4 qb = ld4s((P), gj0,     v1); \
            float4 qc = ld4s((P), gj0 + 4, v2); \
            Wv[0]=qa.x; Wv[1]=qa.y; Wv[2]=qa.z;  Wv[3]=qa.w; \
            Wv[4]=qb.x; Wv[5]=qb.y; Wv[6]=qb.z;  Wv[7]=qb.w; \
            Wv[8]=qc.x; Wv[9]=qc.y; Wv[10]=qc.z; Wv[11]=qc.w; }
            float aw[12], bw[12], cw[12], yw[12];
            LOADW(aw, ar); LOADW(bw, br); LOADW(cw, cr); LOADW(yw, yr);
#undef LOADW
            float hs[13][4];
            HBOX(0,  aw[k]);
            HBOX(1,  bw[k]);
            HBOX(2,  cw[k]);
            HBOX(3,  yw[k]);
            HBOX(4,  yw[k] * aw[k]);
            HBOX(5,  yw[k] * bw[k]);
            HBOX(6,  yw[k] * cw[k]);
            HBOX(7,  aw[k] * aw[k]);
            HBOX(8,  aw[k] * bw[k]);
            HBOX(9,  aw[k] * cw[k]);
            HBOX(10, bw[k] * bw[k]);
            HBOX(11, bw[k] * cw[k]);
            HBOX(12, cw[k] * cw[k]);
#pragma unroll
            for (int c = 0; c < 4; ++c) {
                pA[r * PST + hc + c] = pack4(make_float4(hs[0][c], hs[1][c], hs[2][c],  hs[3][c]));
                pB[r * PST + hc + c] = pack4(make_float4(hs[4][c], hs[5][c], hs[6][c],  hs[7][c]));
                pC[r * PST + hc + c] = pack4(make_float4(hs[8][c], hs[9][c], hs[10][c], hs[11][c]));
                pD[r * PST + hc + c] = __float2half(hs[12][c]);
            }
        } else {
            const h4v z = pack4(make_float4(0.f, 0.f, 0.f, 0.f));
#pragma unroll
            for (int c = 0; c < 4; ++c) {
                pA[r * PST + hc + c] = z; pB[r * PST + hc + c] = z;
                pC[r * PST + hc + c] = z; pD[r * PST + hc + c] = __float2half(0.f);
            }
        }
    }
    __syncthreads();

    // ---- stage 2a: packed-fp16 vertical 9-sum (sliding quad) + f32 solve -> ABh ----
    if (tid < 400) {
        const int c   = tid % 40;
        const int rp  = tid / 40;               // 0..9
        const int rab = rp << 2;                // AB rows rab..rab+3

        __half2 a0, a1, b0, b1, c0, c1;
        __half  dd;
        {
            const int o = rab * PST + c;
            a0 = pA[o].lo; a1 = pA[o].hi;
            b0 = pB[o].lo; b1 = pB[o].hi;
            c0 = pC[o].lo; c1 = pC[o].hi;
            dd = pD[o];
        }
#pragma unroll
        for (int k = 1; k < 9; ++k) {
            const int o = (rab + k) * PST + c;
            a0 = __hadd2(a0, pA[o].lo); a1 = __hadd2(a1, pA[o].hi);
            b0 = __hadd2(b0, pB[o].lo); b1 = __hadd2(b1, pB[o].hi);
            c0 = __hadd2(c0, pC[o].lo); c1 = __hadd2(c1, pC[o].hi);
            dd = __hadd(dd, pD[o]);
        }

        const int gj = tj - 4 + c;
        const bool cv = (unsigned)gj < (unsigned)WW;
        const int j0r = gj - RR < 0 ? 0 : gj - RR;
        const int j1r = gj + RR > WW - 1 ? WW - 1 : gj + RR;
        const float wcnt = (float)(j1r - j0r + 1);
        const float4 z4 = make_float4(0.f, 0.f, 0.f, 0.f);

#define SOLVH(RO) { \
        const int I = ti - 4 + (RO); \
        const bool rv = (unsigned)I < (unsigned)HH; \
        const int i0r = I - RR < 0 ? 0 : I - RR; \
        const int i1r = I + RR > HH - 1 ? HH - 1 : I + RR; \
        const float invn = 1.0f / ((float)(i1r - i0r + 1) * wcnt); \
        float2 xa0 = __half22float2(a0), xa1 = __half22float2(a1); \
        float2 xb0 = __half22float2(b0), xb1 = __half22float2(b1); \
        float2 xc0 = __half22float2(c0), xc1 = __half22float2(c1); \
        float  xd  = __half2float(dd); \
        float4 res = solve_px(make_float4(xa0.x, xa0.y, xa1.x, xa1.y), \
                              make_float4(xb0.x, xb0.y, xb1.x, xb1.y), \
                              make_float4(xc0.x, xc0.y, xc1.x, xc1.y), xd, invn); \
        ABh[(RO) * PST + c] = pack4((cv && rv) ? res : z4); }

#define SLID(RO, RN) { \
        const int o1 = (RO) * PST + c, o2 = (RN) * PST + c; \
        a0 = __hadd2(__hsub2(a0, pA[o1].lo), pA[o2].lo); \
        a1 = __hadd2(__hsub2(a1, pA[o1].hi), pA[o2].hi); \
        b0 = __hadd2(__hsub2(b0, pB[o1].lo), pB[o2].lo); \
        b1 = __hadd2(__hsub2(b1, pB[o1].hi), pB[o2].hi); \
        c0 = __hadd2(__hsub2(c0, pC[o1].lo), pC[o2].lo); \
        c1 = __hadd2(__hsub2(c1, pC[o1].hi), pC[o2].hi); \
        dd = __hadd(__hsub(dd, pD[o1]), pD[o2]); }

        SOLVH(rab)
        SLID(rab,     rab + 9)
        SOLVH(rab + 1)
        SLID(rab + 1, rab + 10)
        SOLVH(rab + 2)
        SLID(rab + 2, rab + 11)
        SOLVH(rab + 3)
#undef SOLVH
#undef SLID
    }
    __syncthreads();

    // ---- stage 2b: packed-fp16 horizontal 9-SUM of ABh -> Ahs[40][33] ----
    if (tid < 320) {
        const int rab = tid >> 3;               // 0..39
        const int q   = tid & 7;                // 0..7
        const int lc  = q << 2;
        h4v wv[12];
#pragma unroll
        for (int k = 0; k < 12; ++k) wv[k] = ABh[rab * PST + lc + k];
        __half2 lo = wv[0].lo, hi = wv[0].hi;
#pragma unroll
        for (int k = 1; k < 9; ++k) { lo = __hadd2(lo, wv[k].lo); hi = __hadd2(hi, wv[k].hi); }
        h4v t; t.lo = lo; t.hi = hi;
        Ahs[rab * AST + lc + 0] = t;
#pragma unroll
        for (int s = 0; s < 3; ++s) {
            lo = __hadd2(__hsub2(lo, wv[s].lo), wv[s + 9].lo);
            hi = __hadd2(__hsub2(hi, wv[s].hi), wv[s + 9].hi);
            t.lo = lo; t.hi = hi;
            Ahs[rab * AST + lc + 1 + s] = t;
        }
    }
    __syncthreads();

    // ---- stage 3: packed-fp16 vertical 9-sum of Ahs + /N + combine (f32) ----
    {
        const int c3 = tid & 31;
        const int r0 = (tid >> 5) << 1;         // out rows r0, r0+1 (0..31)

        const h4v f0 = Ahs[r0 * AST + c3];
        __half2 slo = f0.lo, shi = f0.hi;
#pragma unroll
        for (int k = 1; k < 9; ++k) {
            const h4v v = Ahs[(r0 + k) * AST + c3];
            slo = __hadd2(slo, v.lo); shi = __hadd2(shi, v.hi);
        }

        const int gj  = tj + c3;
        const int j0r = gj - RR < 0 ? 0 : gj - RR;
        const int j1r = gj + RR > WW - 1 ? WW - 1 : gj + RR;
        const float jcnt = (float)(j1r - j0r + 1);

        float* op = out + (size_t)n * plane;

#define FIN(I) { \
        const int i0r = (I) - RR < 0 ? 0 : (I) - RR; \
        const int i1r = (I) + RR > HH - 1 ? HH - 1 : (I) + RR; \
        const float invn = 1.0f / ((float)(i1r - i0r + 1) * jcnt); \
        float2 flo = __half22float2(slo), fhi = __half22float2(shi); \
        const size_t px = (size_t)(I) * WW + gj; \
        const float x0 = xp[px]; \
        const float x1 = xp[px + plane]; \
        const float x2 = xp[px + 2 * plane]; \
        op[px] = (flo.x * x0 + flo.y * x1 + fhi.x * x2 + fhi.y) * invn; }

        FIN(ti + r0);
        {
            const h4v v9 = Ahs[(r0 + 9) * AST + c3];
            slo = __hadd2(__hsub2(slo, f0.lo), v9.lo);
            shi = __hadd2(__hsub2(shi, f0.hi), v9.hi);
        }
        FIN(ti + r0 + 1);
#undef FIN
    }
}

extern "C" void kernel_launch(void* const* d_in, const int* in_sizes, int n_in,
                              void* d_out, int out_size, void* d_ws, size_t ws_size,
                              hipStream_t stream) {
    const float* y = (const float*)d_in[0];   // (4,1,512,512)
    const float* x = (const float*)d_in[1];   // (4,3,512,512)
    float* out = (float*)d_out;               // (4,1,512,512)

    k_all<<<dim3(1024), dim3(512), 0, stream>>>(y, x, out);
}